// Round 10
// baseline (3163.105 us; speedup 1.0000x reference)
//
#include <hip/hip_runtime.h>
#include <math.h>

#define SEQ   2048
#define BATCH 64
#define IN    256
#define HID   256

typedef _Float16 hf2 __attribute__((ext_vector_type(2)));
typedef _Float16 hf4 __attribute__((ext_vector_type(4)));
typedef _Float16 hf8 __attribute__((ext_vector_type(8)));
typedef float    f32x4 __attribute__((ext_vector_type(4)));

static __device__ __forceinline__ float fast_sigmoid(float x) {
    return __builtin_amdgcn_rcpf(1.0f + __expf(-x));
}

static __device__ __forceinline__ float fast_tanh(float x) {
    // tanh(x) = 2/(1+exp(-2x)) - 1
    const float e = __expf(-2.0f * x);
    return fmaf(2.0f, __builtin_amdgcn_rcpf(1.0f + e), -1.0f);
}

static __device__ __forceinline__ hf8 cvt8(const float4& a, const float4& b) {
    hf8 f;
    f[0] = (_Float16)a.x; f[1] = (_Float16)a.y;
    f[2] = (_Float16)a.z; f[3] = (_Float16)a.w;
    f[4] = (_Float16)b.x; f[5] = (_Float16)b.y;
    f[6] = (_Float16)b.z; f[7] = (_Float16)b.w;
    return f;
}

// Workgroup barrier WITHOUT the vmcnt(0) drain __syncthreads() implies.
// LDS ordering (lgkmcnt) is all the h double-buffer needs; global prefetch
// loads / h stores stay in flight across steps (the whole point).
static __device__ __forceinline__ void wg_sync_lds() {
    asm volatile("s_waitcnt lgkmcnt(0)" ::: "memory");
    __builtin_amdgcn_sched_barrier(0);
    __builtin_amdgcn_s_barrier();
    __builtin_amdgcn_sched_barrier(0);
}

// ---------------------------------------------------------------------------
// Kernel 0: Wz,Wh fp32 -> W16 [512][256] fp16 (rows 0-255 = Wz, 256-511 = Wh)
// ---------------------------------------------------------------------------
__global__ __launch_bounds__(256) void w16_kernel(
    const float* __restrict__ Wz, const float* __restrict__ Wh,
    _Float16* __restrict__ W16)
{
    const int idx = blockIdx.x * 256 + threadIdx.x;
    const int row = idx >> 8;
    const int col = idx & 255;
    const float v = (row < 256) ? Wz[row * 256 + col] : Wh[(row - 256) * 256 + col];
    W16[idx] = (_Float16)v;
}

// ---------------------------------------------------------------------------
// Kernel A: input projections via mfma_f32_16x16x32_f16 (validated R4+).
// xz+bz+cz -> xz16 (fp16, d_ws); xh+bh+ch -> d_out fp32 (consumed by rec).
// ---------------------------------------------------------------------------
__global__ __launch_bounds__(256) void proj_mfma_kernel(
    const float* __restrict__ x,
    const _Float16* __restrict__ W16,
    const float* __restrict__ bz, const float* __restrict__ cz,
    const float* __restrict__ bh, const float* __restrict__ ch,
    _Float16* __restrict__ xz16,
    float* __restrict__ xh_out)
{
    const int tid  = threadIdx.x;
    const int lane = tid & 63;
    const int w    = tid >> 6;
    const int m0   = blockIdx.x * 16;
    const int col0 = w * 128;

    const int r = lane & 15;
    const int g = lane >> 4;

    f32x4 acc[8] = {f32x4{0,0,0,0}, f32x4{0,0,0,0}, f32x4{0,0,0,0}, f32x4{0,0,0,0},
                    f32x4{0,0,0,0}, f32x4{0,0,0,0}, f32x4{0,0,0,0}, f32x4{0,0,0,0}};

    const float*    xrow  = x   + (size_t)(m0 + r) * IN + g * 8;
    const _Float16* wbase = W16 + (size_t)(col0 + r) * IN + g * 8;

#pragma unroll
    for (int kt = 0; kt < 8; ++kt) {
        const float4 xa = *reinterpret_cast<const float4*>(xrow + kt * 32);
        const float4 xb = *reinterpret_cast<const float4*>(xrow + kt * 32 + 4);
        const hf8 a = cvt8(xa, xb);
#pragma unroll
        for (int t = 0; t < 8; ++t) {
            const hf8 bfrag = *reinterpret_cast<const hf8*>(
                wbase + (size_t)t * 16 * IN + kt * 32);
            acc[t] = __builtin_amdgcn_mfma_f32_16x16x32_f16(a, bfrag, acc[t], 0, 0, 0);
        }
    }

    if (w < 2) {
#pragma unroll
        for (int t = 0; t < 8; ++t) {
            const int c = col0 + t * 16 + r;
            const float bsum = bz[c] + cz[c];
#pragma unroll
            for (int reg = 0; reg < 4; ++reg) {
                const int m = m0 + 4 * g + reg;
                xz16[(size_t)m * HID + c] = (_Float16)(acc[t][reg] + bsum);
            }
        }
    } else {
#pragma unroll
        for (int t = 0; t < 8; ++t) {
            const int c = col0 - 256 + t * 16 + r;
            const float bsum = bh[c] + ch[c];
#pragma unroll
            for (int reg = 0; reg < 4; ++reg) {
                const int m = m0 + 4 * g + reg;
                xh_out[(size_t)m * HID + c] = acc[t][reg] + bsum;
            }
        }
    }
}

// ---------------------------------------------------------------------------
// Kernel B: MFMA recurrence, D = U . h^T (structure = R8/R9) with:
//  1. raw s_barrier + lgkmcnt(0) per step (NO vmcnt drain -> prefetch loads
//     and h stores stay in flight across the barrier; __syncthreads() was
//     draining ~900cy of HBM latency onto every step's critical path)
//  2. pointer-increment global addressing (row-stride bumps + imm offsets);
//     prefetch reads one row past the end on the last step (lands in
//     h_final / W16 regions -- allocated, values unused).
// ---------------------------------------------------------------------------
__global__ __launch_bounds__(512, 2) void rec_mfma_kernel(
    const float* __restrict__ hidden0,
    const float* __restrict__ Uz,
    const float* __restrict__ Uh,
    const _Float16* __restrict__ xz16,
    float* __restrict__ out,
    float* __restrict__ h_final)
{
    const int wg   = blockIdx.x;        // 0..3
    const int b0   = wg * 16;           // batch base
    const int tid  = threadIdx.x;
    const int w    = tid >> 6;          // wave 0..7
    const int lane = tid & 63;
    const int r    = lane & 15;         // batch (B/C/D col) | U row-in-tile (A)
    const int g    = lane >> 4;         // k-group / reg-group
    const int cb   = 32 * w;            // wave's col window base

    __shared__ __align__(16) _Float16 hbuf[2][16 * 256];

    // ---- A-fragments: U register-resident fp16 (128 VGPRs) ----
    hf8 auz0[8], auz1[8], auh0[8], auh1[8];
#pragma unroll
    for (int kt = 0; kt < 8; ++kt) {
        const size_t ko = (size_t)kt * 32 + 8 * g;
        const float* p;
        p = Uz + (size_t)(cb + r) * HID + ko;
        auz0[kt] = cvt8(*reinterpret_cast<const float4*>(p),
                        *reinterpret_cast<const float4*>(p + 4));
        p = Uz + (size_t)(cb + 16 + r) * HID + ko;
        auz1[kt] = cvt8(*reinterpret_cast<const float4*>(p),
                        *reinterpret_cast<const float4*>(p + 4));
        p = Uh + (size_t)(cb + r) * HID + ko;
        auh0[kt] = cvt8(*reinterpret_cast<const float4*>(p),
                        *reinterpret_cast<const float4*>(p + 4));
        p = Uh + (size_t)(cb + 16 + r) * HID + ko;
        auh1[kt] = cvt8(*reinterpret_cast<const float4*>(p),
                        *reinterpret_cast<const float4*>(p + 4));
    }

    // ---- init hbuf[0] (swizzled blocks) ----
    {
        const int row = tid >> 5;            // batch-in-WG 0..15
        const int blk = tid & 31;            // 8-col block 0..31
        const float4 v0 = *reinterpret_cast<const float4*>(
            hidden0 + (size_t)(b0 + row) * HID + blk * 8);
        const float4 v1 = *reinterpret_cast<const float4*>(
            hidden0 + (size_t)(b0 + row) * HID + blk * 8 + 4);
        *reinterpret_cast<hf8*>(
            &hbuf[0][row * 256 + ((blk ^ (row & 7)) << 3)]) = cvt8(v0, v1);
    }

    // ---- fp32 h state: lane owns (batch r, cols cb+4g+reg and +16) ----
    float hp0[4], hp1[4];
#pragma unroll
    for (int reg = 0; reg < 4; ++reg) {
        hp0[reg] = hidden0[(size_t)(b0 + r) * HID + cb + 4 * g + reg];
        hp1[reg] = hidden0[(size_t)(b0 + r) * HID + cb + 16 + 4 * g + reg];
    }

    // ---- stream pointers (bump by one row per step) ----
    const size_t lane_off = (size_t)(b0 + r) * HID + cb + 4 * g;
    const _Float16* pxz = xz16 + lane_off;   // next xz row to load
    const float*    pxh = out  + lane_off;   // next staged-xh row to load
    float*          pst = out  + lane_off;   // current h row to store

    // ---- prefetch t=0 ----
    hf4   pz0, pz1;
    float4 ph0, ph1;
    pz0 = *reinterpret_cast<const hf4*>(pxz);
    pz1 = *reinterpret_cast<const hf4*>(pxz + 16);
    ph0 = *reinterpret_cast<const float4*>(pxh);
    ph1 = *reinterpret_cast<const float4*>(pxh + 16);
    pxz += (size_t)BATCH * HID;
    pxh += (size_t)BATCH * HID;
    __syncthreads();

    const int rx = r & 7;

#define REC_STEP(CUR, NXT)                                                     \
    {                                                                          \
        /* B-fragments (h^T) from hbuf[CUR] */                                 \
        hf8 bfr[8];                                                            \
        _Pragma("unroll")                                                      \
        for (int kt = 0; kt < 8; ++kt) {                                       \
            bfr[kt] = *reinterpret_cast<const hf8*>(                           \
                &hbuf[CUR][r * 256 + ((((kt << 2) | g) ^ rx) << 3)]);          \
        }                                                                      \
        /* C init = staged xz / xh */                                          \
        f32x4 az0{(float)pz0[0], (float)pz0[1], (float)pz0[2], (float)pz0[3]}; \
        f32x4 az1{(float)pz1[0], (float)pz1[1], (float)pz1[2], (float)pz1[3]}; \
        f32x4 ah0{ph0.x, ph0.y, ph0.z, ph0.w};                                 \
        f32x4 ah1{ph1.x, ph1.y, ph1.z, ph1.w};                                 \
        /* prefetch next row (one past end on last step: allocated, unused) */ \
        pz0 = *reinterpret_cast<const hf4*>(pxz);                              \
        pz1 = *reinterpret_cast<const hf4*>(pxz + 16);                         \
        ph0 = *reinterpret_cast<const float4*>(pxh);                           \
        ph1 = *reinterpret_cast<const float4*>(pxh + 16);                      \
        pxz += (size_t)BATCH * HID;                                            \
        pxh += (size_t)BATCH * HID;                                            \
        _Pragma("unroll")                                                      \
        for (int kt = 0; kt < 8; ++kt) {                                       \
            az0 = __builtin_amdgcn_mfma_f32_16x16x32_f16(auz0[kt], bfr[kt], az0, 0, 0, 0); \
            az1 = __builtin_amdgcn_mfma_f32_16x16x32_f16(auz1[kt], bfr[kt], az1, 0, 0, 0); \
            ah0 = __builtin_amdgcn_mfma_f32_16x16x32_f16(auh0[kt], bfr[kt], ah0, 0, 0, 0); \
            ah1 = __builtin_amdgcn_mfma_f32_16x16x32_f16(auh1[kt], bfr[kt], ah1, 0, 0, 0); \
        }                                                                      \
        /* epilogue: 4 consecutive cols per tile per lane */                   \
        _Pragma("unroll")                                                      \
        for (int reg = 0; reg < 4; ++reg) {                                    \
            const float z0 = fast_sigmoid(az0[reg]);                           \
            const float t0 = fast_tanh(ah0[reg]);                              \
            hp0[reg] = fmaf(z0, t0 - hp0[reg], hp0[reg]);                      \
            const float z1 = fast_sigmoid(az1[reg]);                           \
            const float t1 = fast_tanh(ah1[reg]);                              \
            hp1[reg] = fmaf(z1, t1 - hp1[reg], hp1[reg]);                      \
        }                                                                      \
        *reinterpret_cast<float4*>(pst)      =                                 \
            float4{hp0[0], hp0[1], hp0[2], hp0[3]};                            \
        *reinterpret_cast<float4*>(pst + 16) =                                 \
            float4{hp1[0], hp1[1], hp1[2], hp1[3]};                            \
        pst += (size_t)BATCH * HID;                                            \
        /* pack + swizzled b64 LDS writes */                                   \
        {                                                                      \
            const hf4 pk0{(_Float16)hp0[0], (_Float16)hp0[1],                  \
                          (_Float16)hp0[2], (_Float16)hp0[3]};                 \
            const hf4 pk1{(_Float16)hp1[0], (_Float16)hp1[1],                  \
                          (_Float16)hp1[2], (_Float16)hp1[3]};                 \
            const int blk0 = (cb + 4 * g) >> 3;                                \
            const int blk1 = (cb + 16 + 4 * g) >> 3;                           \
            const int off  = (g & 1) * 4;                                      \
            *reinterpret_cast<hf4*>(                                           \
                &hbuf[NXT][r * 256 + ((blk0 ^ rx) << 3) + off]) = pk0;         \
            *reinterpret_cast<hf4*>(                                           \
                &hbuf[NXT][r * 256 + ((blk1 ^ rx) << 3) + off]) = pk1;         \
        }                                                                      \
        wg_sync_lds();                                                         \
    }

    for (int t = 0; t < SEQ; t += 2) {
        REC_STEP(0, 1)
        REC_STEP(1, 0)
    }
#undef REC_STEP

    {
        const size_t fb = (size_t)(b0 + r) * HID + cb + 4 * g;
        *reinterpret_cast<float4*>(h_final + fb)      =
            float4{hp0[0], hp0[1], hp0[2], hp0[3]};
        *reinterpret_cast<float4*>(h_final + fb + 16) =
            float4{hp1[0], hp1[1], hp1[2], hp1[3]};
    }
}

extern "C" void kernel_launch(void* const* d_in, const int* in_sizes, int n_in,
                              void* d_out, int out_size, void* d_ws, size_t ws_size,
                              hipStream_t stream) {
    const float* x      = (const float*)d_in[0];
    const float* hidden = (const float*)d_in[1];
    const float* Wz     = (const float*)d_in[2];
    const float* bz     = (const float*)d_in[3];
    const float* Uz     = (const float*)d_in[4];
    const float* cz     = (const float*)d_in[5];
    const float* Wh     = (const float*)d_in[6];
    const float* bh     = (const float*)d_in[7];
    const float* Uh     = (const float*)d_in[8];
    const float* ch     = (const float*)d_in[9];

    float* out     = (float*)d_out;                        // [SEQ*BATCH*HID]
    float* h_final = out + (size_t)SEQ * BATCH * HID;      // [BATCH*HID]

    _Float16* xz16 = (_Float16*)d_ws;                               // 64 MiB
    _Float16* W16  = (_Float16*)((char*)d_ws + ((size_t)64 << 20)); // 256 KiB

    w16_kernel<<<512, 256, 0, stream>>>(Wz, Wh, W16);

    proj_mfma_kernel<<<(SEQ * BATCH) / 16, 256, 0, stream>>>(
        x, W16, bz, cz, bh, ch, xz16, out);

    rec_mfma_kernel<<<4, 512, 0, stream>>>(
        hidden, Uz, Uh, xz16, out, h_final);
}

// Round 11
// 2576.285 us; speedup vs baseline: 1.2278x; 1.2278x over previous
//
#include <hip/hip_runtime.h>
#include <math.h>

#define SEQ   2048
#define BATCH 64
#define IN    256
#define HID   256

typedef _Float16 hf2 __attribute__((ext_vector_type(2)));
typedef _Float16 hf4 __attribute__((ext_vector_type(4)));
typedef _Float16 hf8 __attribute__((ext_vector_type(8)));
typedef float    f32x4 __attribute__((ext_vector_type(4)));

static __device__ __forceinline__ float fast_sigmoid(float x) {
    return __builtin_amdgcn_rcpf(1.0f + __expf(-x));
}

static __device__ __forceinline__ float fast_tanh(float x) {
    // tanh(x) = 2/(1+exp(-2x)) - 1
    const float e = __expf(-2.0f * x);
    return fmaf(2.0f, __builtin_amdgcn_rcpf(1.0f + e), -1.0f);
}

static __device__ __forceinline__ hf8 cvt8(const float4& a, const float4& b) {
    hf8 f;
    f[0] = (_Float16)a.x; f[1] = (_Float16)a.y;
    f[2] = (_Float16)a.z; f[3] = (_Float16)a.w;
    f[4] = (_Float16)b.x; f[5] = (_Float16)b.y;
    f[6] = (_Float16)b.z; f[7] = (_Float16)b.w;
    return f;
}

// ---------------------------------------------------------------------------
// Kernel 0: Wz,Wh fp32 -> W16 [512][256] fp16 (rows 0-255 = Wz, 256-511 = Wh)
// ---------------------------------------------------------------------------
__global__ __launch_bounds__(256) void w16_kernel(
    const float* __restrict__ Wz, const float* __restrict__ Wh,
    _Float16* __restrict__ W16)
{
    const int idx = blockIdx.x * 256 + threadIdx.x;
    const int row = idx >> 8;
    const int col = idx & 255;
    const float v = (row < 256) ? Wz[row * 256 + col] : Wh[(row - 256) * 256 + col];
    W16[idx] = (_Float16)v;
}

// ---------------------------------------------------------------------------
// Kernel A: input projections via mfma_f32_16x16x32_f16 (validated R4+).
// xz+bz+cz -> xz16 (fp16, d_ws); xh+bh+ch -> d_out fp32 (consumed by rec).
// ---------------------------------------------------------------------------
__global__ __launch_bounds__(256) void proj_mfma_kernel(
    const float* __restrict__ x,
    const _Float16* __restrict__ W16,
    const float* __restrict__ bz, const float* __restrict__ cz,
    const float* __restrict__ bh, const float* __restrict__ ch,
    _Float16* __restrict__ xz16,
    float* __restrict__ xh_out)
{
    const int tid  = threadIdx.x;
    const int lane = tid & 63;
    const int w    = tid >> 6;
    const int m0   = blockIdx.x * 16;
    const int col0 = w * 128;

    const int r = lane & 15;
    const int g = lane >> 4;

    f32x4 acc[8] = {f32x4{0,0,0,0}, f32x4{0,0,0,0}, f32x4{0,0,0,0}, f32x4{0,0,0,0},
                    f32x4{0,0,0,0}, f32x4{0,0,0,0}, f32x4{0,0,0,0}, f32x4{0,0,0,0}};

    const float*    xrow  = x   + (size_t)(m0 + r) * IN + g * 8;
    const _Float16* wbase = W16 + (size_t)(col0 + r) * IN + g * 8;

#pragma unroll
    for (int kt = 0; kt < 8; ++kt) {
        const float4 xa = *reinterpret_cast<const float4*>(xrow + kt * 32);
        const float4 xb = *reinterpret_cast<const float4*>(xrow + kt * 32 + 4);
        const hf8 a = cvt8(xa, xb);
#pragma unroll
        for (int t = 0; t < 8; ++t) {
            const hf8 bfrag = *reinterpret_cast<const hf8*>(
                wbase + (size_t)t * 16 * IN + kt * 32);
            acc[t] = __builtin_amdgcn_mfma_f32_16x16x32_f16(a, bfrag, acc[t], 0, 0, 0);
        }
    }

    if (w < 2) {
#pragma unroll
        for (int t = 0; t < 8; ++t) {
            const int c = col0 + t * 16 + r;
            const float bsum = bz[c] + cz[c];
#pragma unroll
            for (int reg = 0; reg < 4; ++reg) {
                const int m = m0 + 4 * g + reg;
                xz16[(size_t)m * HID + c] = (_Float16)(acc[t][reg] + bsum);
            }
        }
    } else {
#pragma unroll
        for (int t = 0; t < 8; ++t) {
            const int c = col0 - 256 + t * 16 + r;
            const float bsum = bh[c] + ch[c];
#pragma unroll
            for (int reg = 0; reg < 4; ++reg) {
                const int m = m0 + 4 * g + reg;
                xh_out[(size_t)m * HID + c] = acc[t][reg] + bsum;
            }
        }
    }
}

// ---------------------------------------------------------------------------
// Kernel B: MFMA recurrence, ONE WG PER BATCH (64 WGs = 64 CUs).
// D = U_int . (h ⊗ 1^T):
//   - B-fragment: all lanes read the SAME 16B of LDS h (uniform addr ->
//     hardware broadcast, no redundant LDS bandwidth). Every D column is
//     then identical; column r==0 is "the" result, resident in ALL lanes.
//   - A = U with Uz/Uh rows INTERLEAVED pairwise (row 2o=Uz[o], 2o+1=Uh[o]),
//     register-resident fp16 (4 tiles x 8 kt x hf8 = 128 VGPRs). M = 512
//     interleaved rows = zero M-waste; acc regs per lane/tile =
//     {z[o], h~[o], z[o+1], h~[o+1]} -> gates co-located, no exchange.
//   - Epilogue computed by ALL lanes (values replicated across r -> no
//     divergence); only r==0 lanes store (float2 to out, hf2 to LDS h).
//   - LDS h: 256 fp16 = 512 B, double-buffered. xz16 is MFMA C-init;
//     next-step xz/xh prefetched before the MFMA block. 1 barrier/step.
// Per wave/step: 8 broadcast ds_read_b128 + 32 MFMA + ~25 VALU/out-pair.
// ---------------------------------------------------------------------------
__global__ __launch_bounds__(512, 2) void rec_mfma_kernel(
    const float* __restrict__ hidden0,
    const float* __restrict__ Uz,
    const float* __restrict__ Uh,
    const _Float16* __restrict__ xz16,
    float* __restrict__ out,
    float* __restrict__ h_final)
{
    const int b    = blockIdx.x;        // batch element (one per WG)
    const int tid  = threadIdx.x;
    const int w    = tid >> 6;          // wave 0..7
    const int lane = tid & 63;
    const int r    = lane & 15;         // A-row within tile (interleaved)
    const int g    = lane >> 4;         // k-group / reg-group

    __shared__ __align__(16) _Float16 hbuf[2][256];

    // ---- A-fragments: interleaved U, register-resident ----
    // tile i (global m = 4w+i) covers interleaved rows [16m,16m+16)
    //   row 16m + rr  <->  (rr&1 ? Uh : Uz)[8m + (rr>>1)]
    hf8 au[4][8];
    {
        const float* usrc = (r & 1) ? Uh : Uz;
        const int    hrow = r >> 1;
#pragma unroll
        for (int i = 0; i < 4; ++i) {
            const int m = 4 * w + i;
            const float* p0 = usrc + (size_t)(8 * m + hrow) * HID;
#pragma unroll
            for (int kt = 0; kt < 8; ++kt) {
                const float* p = p0 + kt * 32 + 8 * g;
                au[i][kt] = cvt8(*reinterpret_cast<const float4*>(p),
                                 *reinterpret_cast<const float4*>(p + 4));
            }
        }
    }

    // ---- init LDS h + fp32 h state ----
    if (tid < 256) {
        hbuf[0][tid] = (_Float16)hidden0[b * HID + tid];
    }
    // lane (g, tile i): outs o_i = 8*(4w+i) + 2g and o_i+1
    float hp[4][2];
#pragma unroll
    for (int i = 0; i < 4; ++i) {
        const int o = 8 * (4 * w + i) + 2 * g;
        hp[i][0] = hidden0[b * HID + o];
        hp[i][1] = hidden0[b * HID + o + 1];
    }

    // ---- stream pointers + t=0 prefetch ----
    const _Float16* pxz[4];
    const float*    pxh[4];
    float*          pst[4];
    hf2    qz[4];
    float2 qh[4];
#pragma unroll
    for (int i = 0; i < 4; ++i) {
        const int o = 8 * (4 * w + i) + 2 * g;
        pxz[i] = xz16 + (size_t)b * HID + o;
        pxh[i] = out  + (size_t)b * HID + o;
        pst[i] = out  + (size_t)b * HID + o;
        qz[i] = *reinterpret_cast<const hf2*>(pxz[i]);
        qh[i] = *reinterpret_cast<const float2*>(pxh[i]);
        pxz[i] += (size_t)BATCH * HID;
        pxh[i] += (size_t)BATCH * HID;
    }
    __syncthreads();

#define REC_STEP(CUR, NXT)                                                     \
    {                                                                          \
        /* broadcast B-fragments: uniform address across all lanes */          \
        hf8 bb[8];                                                             \
        _Pragma("unroll")                                                      \
        for (int kt = 0; kt < 8; ++kt) {                                       \
            bb[kt] = *reinterpret_cast<const hf8*>(                            \
                &hbuf[CUR][kt * 32 + 8 * g]);                                  \
        }                                                                      \
        /* C init: {z[o], h~[o], z[o+1], h~[o+1]} from staged xz/xh */         \
        f32x4 acc[4];                                                          \
        _Pragma("unroll")                                                      \
        for (int i = 0; i < 4; ++i) {                                          \
            acc[i] = f32x4{(float)qz[i][0], qh[i].x,                           \
                           (float)qz[i][1], qh[i].y};                          \
        }                                                                      \
        /* prefetch next row (one past end on last step: allocated, unused) */ \
        _Pragma("unroll")                                                      \
        for (int i = 0; i < 4; ++i) {                                          \
            qz[i] = *reinterpret_cast<const hf2*>(pxz[i]);                     \
            qh[i] = *reinterpret_cast<const float2*>(pxh[i]);                  \
            pxz[i] += (size_t)BATCH * HID;                                     \
            pxh[i] += (size_t)BATCH * HID;                                     \
        }                                                                      \
        _Pragma("unroll")                                                      \
        for (int kt = 0; kt < 8; ++kt) {                                       \
            _Pragma("unroll")                                                  \
            for (int i = 0; i < 4; ++i) {                                      \
                acc[i] = __builtin_amdgcn_mfma_f32_16x16x32_f16(               \
                    au[i][kt], bb[kt], acc[i], 0, 0, 0);                       \
            }                                                                  \
        }                                                                      \
        /* epilogue (all lanes, replicated across r; only r==0 writes) */      \
        _Pragma("unroll")                                                      \
        for (int i = 0; i < 4; ++i) {                                          \
            const float z0 = fast_sigmoid(acc[i][0]);                          \
            const float t0 = fast_tanh(acc[i][1]);                             \
            const float h0 = fmaf(z0, t0 - hp[i][0], hp[i][0]);                \
            const float z1 = fast_sigmoid(acc[i][2]);                          \
            const float t1 = fast_tanh(acc[i][3]);                             \
            const float h1 = fmaf(z1, t1 - hp[i][1], hp[i][1]);                \
            hp[i][0] = h0;                                                     \
            hp[i][1] = h1;                                                     \
            if (r == 0) {                                                      \
                *reinterpret_cast<float2*>(pst[i]) = float2{h0, h1};           \
                const int o = 8 * (4 * w + i) + 2 * g;                         \
                *reinterpret_cast<hf2*>(&hbuf[NXT][o]) =                       \
                    hf2{(_Float16)h0, (_Float16)h1};                           \
            }                                                                  \
            pst[i] += (size_t)BATCH * HID;                                     \
        }                                                                      \
        __syncthreads();                                                       \
    }

    for (int t = 0; t < SEQ; t += 2) {
        REC_STEP(0, 1)
        REC_STEP(1, 0)
    }
#undef REC_STEP

    if (r == 0) {
#pragma unroll
        for (int i = 0; i < 4; ++i) {
            const int o = 8 * (4 * w + i) + 2 * g;
            *reinterpret_cast<float2*>(h_final + (size_t)b * HID + o) =
                float2{hp[i][0], hp[i][1]};
        }
    }
}

extern "C" void kernel_launch(void* const* d_in, const int* in_sizes, int n_in,
                              void* d_out, int out_size, void* d_ws, size_t ws_size,
                              hipStream_t stream) {
    const float* x      = (const float*)d_in[0];
    const float* hidden = (const float*)d_in[1];
    const float* Wz     = (const float*)d_in[2];
    const float* bz     = (const float*)d_in[3];
    const float* Uz     = (const float*)d_in[4];
    const float* cz     = (const float*)d_in[5];
    const float* Wh     = (const float*)d_in[6];
    const float* bh     = (const float*)d_in[7];
    const float* Uh     = (const float*)d_in[8];
    const float* ch     = (const float*)d_in[9];

    float* out     = (float*)d_out;                        // [SEQ*BATCH*HID]
    float* h_final = out + (size_t)SEQ * BATCH * HID;      // [BATCH*HID]

    _Float16* xz16 = (_Float16*)d_ws;                               // 64 MiB
    _Float16* W16  = (_Float16*)((char*)d_ws + ((size_t)64 << 20)); // 256 KiB

    w16_kernel<<<512, 256, 0, stream>>>(Wz, Wh, W16);

    proj_mfma_kernel<<<(SEQ * BATCH) / 16, 256, 0, stream>>>(
        x, W16, bz, cz, bh, ch, xz16, out);

    rec_mfma_kernel<<<BATCH, 512, 0, stream>>>(
        hidden, Uz, Uh, xz16, out, h_final);
}